// Round 1
// baseline (225.126 us; speedup 1.0000x reference)
//
#include <hip/hip_runtime.h>

// Batched gather-GEMV:
//   out[bp, d] = (sum_h hs[bp, h] * W[props[bp], h, d] + bias[props[bp], d]) * mask[bp]
// B*P = 65536, H = 512, D = 2.
// One wave (64 lanes) per (b,p) pair: lane i owns h = 8i..8i+7.
//   hidden: 2x float4 per lane (coalesced, 2 KB/wave)
//   weights: 4x float4 per lane (coalesced, 4 KB/wave; D=2 innermost)
// Memory-bound: ~180 MB effective HBM traffic -> ~30 us floor.

#define H 512
#define D 2

__global__ __launch_bounds__(256) void adapter_gemv_kernel(
    const float* __restrict__ hs,     // (BP, H)
    const int*   __restrict__ props,  // (BP)
    const float* __restrict__ mask,   // (BP)
    const float* __restrict__ W,      // (NPROP, H, D)
    const float* __restrict__ bias,   // (NPROP, D)
    float* __restrict__ out,          // (BP, D)
    int BP)
{
    const int tid  = blockIdx.x * blockDim.x + threadIdx.x;
    const int bp   = tid >> 6;
    const int lane = tid & 63;
    if (bp >= BP) return;

    const int prop = props[bp];

    const float4* h4 = (const float4*)(hs + (size_t)bp * H) + lane * 2;
    const float4* w4 = (const float4*)(W  + (size_t)prop * (H * D)) + lane * 4;

    float4 ha = h4[0];
    float4 hb = h4[1];
    float4 w0 = w4[0];
    float4 w1 = w4[1];
    float4 w2 = w4[2];
    float4 w3 = w4[3];

    // w4[k] packs (W[h,0], W[h,1], W[h+1,0], W[h+1,1]) for consecutive h.
    float s0 = ha.x * w0.x + ha.y * w0.z + ha.z * w1.x + ha.w * w1.z
             + hb.x * w2.x + hb.y * w2.z + hb.z * w3.x + hb.w * w3.z;
    float s1 = ha.x * w0.y + ha.y * w0.w + ha.z * w1.y + ha.w * w1.w
             + hb.x * w2.y + hb.y * w2.w + hb.z * w3.y + hb.w * w3.w;

    // 64-lane butterfly reduction
    #pragma unroll
    for (int off = 32; off > 0; off >>= 1) {
        s0 += __shfl_down(s0, off, 64);
        s1 += __shfl_down(s1, off, 64);
    }

    if (lane == 0) {
        const float m  = mask[bp];
        const float b0 = bias[(size_t)prop * D + 0];
        const float b1 = bias[(size_t)prop * D + 1];
        float2 r;
        r.x = (s0 + b0) * m;
        r.y = (s1 + b1) * m;
        *(float2*)(out + (size_t)bp * D) = r;
    }
}

extern "C" void kernel_launch(void* const* d_in, const int* in_sizes, int n_in,
                              void* d_out, int out_size, void* d_ws, size_t ws_size,
                              hipStream_t stream) {
    const float* hs    = (const float*)d_in[0];
    const int*   props = (const int*)d_in[1];
    const float* mask  = (const float*)d_in[2];
    const float* W     = (const float*)d_in[3];
    const float* bias  = (const float*)d_in[4];
    float* out = (float*)d_out;

    const int BP = in_sizes[1];          // 512 * 128 = 65536 pairs
    const int threads = 256;             // 4 waves/block
    const int waves_per_block = threads / 64;
    const int blocks = (BP + waves_per_block - 1) / waves_per_block;

    adapter_gemv_kernel<<<blocks, threads, 0, stream>>>(hs, props, mask, W, bias, out, BP);
}

// Round 2
// 223.271 us; speedup vs baseline: 1.0083x; 1.0083x over previous
//
#include <hip/hip_runtime.h>

// Batched gather-GEMV:
//   out[bp, d] = (sum_h hs[bp, h] * W[props[bp], h, d] + bias[props[bp], d]) * mask[bp]
// B*P = 65536, H = 512, D = 2.
//
// One wave per (b,p) pair, COALESCED ownership:
//   iteration k (k=0..3), lane i owns h = {128k + 2i, 128k + 2i + 1}
//     W  chunk: float4  W4[prop*256 + 64k + i]   -> lanes contiguous, 1 KiB/instr
//     hs chunk: float2 hs2[bp*256   + 64k + i]   -> lanes contiguous, 512 B/instr
// Every vector-memory instruction is lane-contiguous (prev version had 64 B
// inter-lane stride -> 4x the granule transactions -> transaction-bound).

#define H 512
#define D 2

__global__ __launch_bounds__(256) void adapter_gemv_kernel(
    const float* __restrict__ hs,     // (BP, H)
    const int*   __restrict__ props,  // (BP)
    const float* __restrict__ mask,   // (BP)
    const float* __restrict__ W,      // (NPROP, H, D)
    const float* __restrict__ bias,   // (NPROP, D)
    float* __restrict__ out,          // (BP, D)
    int BP)
{
    const int tid  = blockIdx.x * blockDim.x + threadIdx.x;
    const int bp   = tid >> 6;
    const int lane = tid & 63;
    if (bp >= BP) return;

    const int prop = props[bp];

    const float2* h2 = (const float2*)(hs + (size_t)bp * H);          // 256 float2
    const float4* w4 = (const float4*)(W + (size_t)prop * (H * D));   // 256 float4

    // Issue all 8 loads up front (memory-level parallelism), compute after.
    float2 ha = h2[lane];
    float2 hb = h2[64 + lane];
    float2 hc = h2[128 + lane];
    float2 hd = h2[192 + lane];
    float4 wa = w4[lane];
    float4 wb = w4[64 + lane];
    float4 wc = w4[128 + lane];
    float4 wd = w4[192 + lane];

    // w4 chunk packs (W[h,0], W[h,1], W[h+1,0], W[h+1,1]); h2 packs (hs[h], hs[h+1]).
    float s0 = ha.x * wa.x + ha.y * wa.z
             + hb.x * wb.x + hb.y * wb.z
             + hc.x * wc.x + hc.y * wc.z
             + hd.x * wd.x + hd.y * wd.z;
    float s1 = ha.x * wa.y + ha.y * wa.w
             + hb.x * wb.y + hb.y * wb.w
             + hc.x * wc.y + hc.y * wc.w
             + hd.x * wd.y + hd.y * wd.w;

    // 64-lane butterfly reduction
    #pragma unroll
    for (int off = 32; off > 0; off >>= 1) {
        s0 += __shfl_xor(s0, off, 64);
        s1 += __shfl_xor(s1, off, 64);
    }

    if (lane == 0) {
        const float m  = mask[bp];
        const float b0 = bias[(size_t)prop * D + 0];
        const float b1 = bias[(size_t)prop * D + 1];
        float2 r;
        r.x = (s0 + b0) * m;
        r.y = (s1 + b1) * m;
        *(float2*)(out + (size_t)bp * D) = r;
    }
}

extern "C" void kernel_launch(void* const* d_in, const int* in_sizes, int n_in,
                              void* d_out, int out_size, void* d_ws, size_t ws_size,
                              hipStream_t stream) {
    const float* hs    = (const float*)d_in[0];
    const int*   props = (const int*)d_in[1];
    const float* mask  = (const float*)d_in[2];
    const float* W     = (const float*)d_in[3];
    const float* bias  = (const float*)d_in[4];
    float* out = (float*)d_out;

    const int BP = in_sizes[1];          // 512 * 128 = 65536 pairs
    const int threads = 256;             // 4 waves/block
    const int waves_per_block = threads / 64;
    const int blocks = (BP + waves_per_block - 1) / waves_per_block;

    adapter_gemv_kernel<<<blocks, threads, 0, stream>>>(hs, props, mask, W, bias, out, BP);
}